// Round 2
// baseline (362.490 us; speedup 1.0000x reference)
//
#include <hip/hip_runtime.h>

#define NN 262144
#define RANK 16
#define NNZ_K 1310720
#define NB 640           // k_bin blocks
#define BPB 2048         // nnz per k_bin block
#define NBKT 256         // row buckets (1024 rows each)
#define RPB 1024         // rows per bucket

struct P8 { const float* p[8]; };

// ---------------------------------------------------------------------------
// K1: per-chunk partials  part[l][c][r] = sum_{j in chunk c} v_l[j][r]*z[j]
// ---------------------------------------------------------------------------
__global__ __launch_bounds__(512) void k_levels_t(P8 v, const float* __restrict__ z,
                                                  float* __restrict__ part) {
    __shared__ float zl[512];
    __shared__ float red[8][8][16];   // [level][wave][rank]
    const int tid  = threadIdx.x;
    const int base = blockIdx.x * 512;

    zl[tid] = z[base + tid];
    __syncthreads();

    const int q = tid & 3;
    const int e = tid >> 2;           // 0..127

    float4 acc[8];
#pragma unroll
    for (int l = 0; l < 8; ++l) acc[l] = make_float4(0.f, 0.f, 0.f, 0.f);

#pragma unroll
    for (int it = 0; it < 4; ++it) {
        const int jloc = it * 128 + e;
        const size_t j = (size_t)(base + jloc);
        const float zz = zl[jloc];
        float4 vv[8];
#pragma unroll
        for (int l = 0; l < 8; ++l)
            vv[l] = *(const float4*)(v.p[l] + j * RANK + q * 4);
#pragma unroll
        for (int l = 0; l < 8; ++l) {
            acc[l].x += vv[l].x * zz;
            acc[l].y += vv[l].y * zz;
            acc[l].z += vv[l].z * zz;
            acc[l].w += vv[l].w * zz;
        }
    }

    const int lane = tid & 63;
    const int wv   = tid >> 6;        // 0..7
#pragma unroll
    for (int l = 0; l < 8; ++l) {
        float4 a = acc[l];
#pragma unroll
        for (int m = 4; m <= 32; m <<= 1) {
            a.x += __shfl_xor(a.x, m);
            a.y += __shfl_xor(a.y, m);
            a.z += __shfl_xor(a.z, m);
            a.w += __shfl_xor(a.w, m);
        }
        if (lane < 4) *(float4*)&red[l][wv][lane * 4] = a;
    }
    __syncthreads();

    if (tid < 128) {
        const int l = tid >> 4;
        const int r = tid & 15;
        float s = 0.f;
#pragma unroll
        for (int k = 0; k < 8; ++k) s += red[l][k][r];
        part[(l * 512 + blockIdx.x) * 16 + r] = s;
    }
}

// ---------------------------------------------------------------------------
// K1b: tg[(l,h)][r] = sum of partials; one block per (l,h). Zeroes loss.
// ---------------------------------------------------------------------------
__global__ __launch_bounds__(64) void k_reduce_t(const float* __restrict__ part,
                                                 float* __restrict__ tg,
                                                 float* __restrict__ loss) {
    const int b = blockIdx.x;
    if (b == 0 && threadIdx.x == 0) loss[0] = 0.f;
    const int t = b + 2;
    const int l = 30 - __clz(t);
    const int h = t - (2 << l);
    const int cnt = 256 >> l;
    const int c0  = h * cnt;
    const int r = threadIdx.x & 15;
    const int g = threadIdx.x >> 4;

    float s = 0.f;
    for (int c = c0 + g; c < c0 + cnt; c += 4)
        s += part[(l * 512 + c) * 16 + r];

    __shared__ float red[64];
    red[threadIdx.x] = s;
    __syncthreads();
    if (threadIdx.x < 16)
        tg[((2 << l) - 2 + h) * 16 + r] = red[r] + red[16 + r] + red[32 + r] + red[48 + r];
}

// ---------------------------------------------------------------------------
// K2a: leaf part, one WAVE per 32x32 leaf block. No LDS, no barriers.
// Lane l: r = l>>1 (row), ch = l&1 (column half, 16 cols). Two matvecs via
// shfl_xor butterflies.  w0[i] = [L (L^T x)]_i + 1e-4 x[i]
// ---------------------------------------------------------------------------
__global__ __launch_bounds__(256) void k_leaf(const float* __restrict__ leaf,
                                              const float* __restrict__ z,
                                              float* __restrict__ w) {
    const int tid = threadIdx.x;
    const int l6  = tid & 63;
    const int b   = blockIdx.x * 4 + (tid >> 6);   // leaf block, one per wave
    const int r   = l6 >> 1;
    const int ch  = l6 & 1;

    const float* Lb = leaf + (size_t)b * 1024 + r * 32 + ch * 16;
    const float4 L0 = ((const float4*)Lb)[0];
    const float4 L1 = ((const float4*)Lb)[1];
    const float4 L2 = ((const float4*)Lb)[2];
    const float4 L3 = ((const float4*)Lb)[3];

    const float zl = z[b * 32 + (l6 & 31)];
    const float xr = __shfl(zl, r);                // x[r]

    // t-partials: this lane's contribution L[r][c]*x[r] for its 16 cols
    float4 t0 = make_float4(L0.x * xr, L0.y * xr, L0.z * xr, L0.w * xr);
    float4 t1 = make_float4(L1.x * xr, L1.y * xr, L1.z * xr, L1.w * xr);
    float4 t2 = make_float4(L2.x * xr, L2.y * xr, L2.z * xr, L2.w * xr);
    float4 t3 = make_float4(L3.x * xr, L3.y * xr, L3.z * xr, L3.w * xr);

    // reduce over r: the 32 lanes sharing parity ch are {l ^ even masks}
#pragma unroll
    for (int m = 2; m <= 32; m <<= 1) {
        t0.x += __shfl_xor(t0.x, m); t0.y += __shfl_xor(t0.y, m);
        t0.z += __shfl_xor(t0.z, m); t0.w += __shfl_xor(t0.w, m);
        t1.x += __shfl_xor(t1.x, m); t1.y += __shfl_xor(t1.y, m);
        t1.z += __shfl_xor(t1.z, m); t1.w += __shfl_xor(t1.w, m);
        t2.x += __shfl_xor(t2.x, m); t2.y += __shfl_xor(t2.y, m);
        t2.z += __shfl_xor(t2.z, m); t2.w += __shfl_xor(t2.w, m);
        t3.x += __shfl_xor(t3.x, m); t3.y += __shfl_xor(t3.y, m);
        t3.z += __shfl_xor(t3.z, m); t3.w += __shfl_xor(t3.w, m);
    }

    // y-partial over this lane's 16 cols, then add the other half (lane^1)
    float yp = L0.x * t0.x + L0.y * t0.y + L0.z * t0.z + L0.w * t0.w
             + L1.x * t1.x + L1.y * t1.y + L1.z * t1.z + L1.w * t1.w
             + L2.x * t2.x + L2.y * t2.y + L2.z * t2.z + L2.w * t2.w
             + L3.x * t3.x + L3.y * t3.y + L3.z * t3.z + L3.w * t3.w;
    yp += __shfl_xor(yp, 1);

    const float w0 = yp + 1e-4f * xr;

    // compact: lane l<32 takes w0 from lane 2l (row l, full sum)
    const float out = __shfl(w0, (l6 & 31) * 2);
    if (l6 < 32) w[(size_t)b * 32 + l6] = out;
}

// ---------------------------------------------------------------------------
// K2b: streaming u-accumulation  w[i] += sum_l u_l[i][:] . t_{l, sibling}
// 128-thread blocks, 512 B LDS, 16 independent float4 loads per phase.
// y-zeroing only used in the fallback path (y may be null).
// ---------------------------------------------------------------------------
__global__ __launch_bounds__(128) void k_uacc(P8 u,
                                              const float* __restrict__ tg,
                                              float* __restrict__ w,
                                              float* __restrict__ y) {
    __shared__ float tl[8][16];
    const int tid  = threadIdx.x;
    const int base = blockIdx.x * 128;
    const size_t i = (size_t)(base + tid);

    // tl table first (tiny, L2-resident tg)
    {
        const int l = tid >> 4;
        const int r = tid & 15;
        const int h = base >> (17 - l);
        tl[l][r] = tg[(((2 << l) - 2) + (h ^ 1)) * 16 + r];
    }

    // issue levels 0..3 (16 independent 16B loads) before the barrier
    float4 a[16];
#pragma unroll
    for (int l = 0; l < 4; ++l) {
        const float4* up = (const float4*)(u.p[l] + i * RANK);
#pragma unroll
        for (int k = 0; k < 4; ++k) a[l * 4 + k] = up[k];
    }
    const float accw = w[i];
    __syncthreads();

    float accs[8];
#pragma unroll
    for (int l = 0; l < 4; ++l) {
        const float4 t0 = *(const float4*)&tl[l][0];
        const float4 t1 = *(const float4*)&tl[l][4];
        const float4 t2 = *(const float4*)&tl[l][8];
        const float4 t3 = *(const float4*)&tl[l][12];
        accs[l] = a[l*4+0].x * t0.x + a[l*4+0].y * t0.y + a[l*4+0].z * t0.z + a[l*4+0].w * t0.w
                + a[l*4+1].x * t1.x + a[l*4+1].y * t1.y + a[l*4+1].z * t1.z + a[l*4+1].w * t1.w
                + a[l*4+2].x * t2.x + a[l*4+2].y * t2.y + a[l*4+2].z * t2.z + a[l*4+2].w * t2.w
                + a[l*4+3].x * t3.x + a[l*4+3].y * t3.y + a[l*4+3].z * t3.z + a[l*4+3].w * t3.w;
    }

#pragma unroll
    for (int l = 0; l < 4; ++l) {
        const float4* up = (const float4*)(u.p[l + 4] + i * RANK);
#pragma unroll
        for (int k = 0; k < 4; ++k) a[l * 4 + k] = up[k];
    }
#pragma unroll
    for (int l = 0; l < 4; ++l) {
        const float4 t0 = *(const float4*)&tl[l + 4][0];
        const float4 t1 = *(const float4*)&tl[l + 4][4];
        const float4 t2 = *(const float4*)&tl[l + 4][8];
        const float4 t3 = *(const float4*)&tl[l + 4][12];
        accs[l + 4] = a[l*4+0].x * t0.x + a[l*4+0].y * t0.y + a[l*4+0].z * t0.z + a[l*4+0].w * t0.w
                    + a[l*4+1].x * t1.x + a[l*4+1].y * t1.y + a[l*4+1].z * t1.z + a[l*4+1].w * t1.w
                    + a[l*4+2].x * t2.x + a[l*4+2].y * t2.y + a[l*4+2].z * t2.z + a[l*4+2].w * t2.w
                    + a[l*4+3].x * t3.x + a[l*4+3].y * t3.y + a[l*4+3].z * t3.z + a[l*4+3].w * t3.w;
    }

    w[i] = accw + ((accs[0] + accs[1]) + (accs[2] + accs[3]))
                + ((accs[4] + accs[5]) + (accs[6] + accs[7]));
    if (y) y[i] = 0.f;
}

// ---------------------------------------------------------------------------
// K3a: bucket-sort (row, val*w[col]) pairs. 512 threads.
// ---------------------------------------------------------------------------
__global__ __launch_bounds__(512) void k_bin(const int* __restrict__ idx,
                                             const float* __restrict__ vals,
                                             const float* __restrict__ w,
                                             unsigned long long* __restrict__ gpairs,
                                             int* __restrict__ gdesc) {
    __shared__ unsigned long long pairs[BPB];   // 16 KB
    __shared__ int hist[NBKT];
    __shared__ int scan[NBKT];
    __shared__ int cursor[NBKT];

    const int t  = threadIdx.x;
    const int bl = blockIdx.x;
    const int base = bl * BPB;

    if (t < NBKT) hist[t] = 0;
    __syncthreads();

    int   rows[4];
    float pv[4];
    {
        const int k = base + t * 4;
        const int4   r4 = *(const int4*)(idx + k);
        const int4   c4 = *(const int4*)(idx + NNZ_K + k);
        const float4 v4 = *(const float4*)(vals + k);
        rows[0] = r4.x; pv[0] = v4.x * w[c4.x];
        rows[1] = r4.y; pv[1] = v4.y * w[c4.y];
        rows[2] = r4.z; pv[2] = v4.z * w[c4.z];
        rows[3] = r4.w; pv[3] = v4.w * w[c4.w];
        atomicAdd(&hist[r4.x >> 10], 1);
        atomicAdd(&hist[r4.y >> 10], 1);
        atomicAdd(&hist[r4.z >> 10], 1);
        atomicAdd(&hist[r4.w >> 10], 1);
    }
    __syncthreads();

    // inclusive Hillis-Steele scan over 256 buckets (first 256 threads)
    int cnt = 0;
    if (t < NBKT) { cnt = hist[t]; scan[t] = cnt; }
    __syncthreads();
    for (int off = 1; off < NBKT; off <<= 1) {
        int add = 0;
        if (t >= off && t < NBKT) add = scan[t - off];
        __syncthreads();
        if (t < NBKT) scan[t] += add;
        __syncthreads();
    }
    if (t < NBKT) {
        const int st = scan[t] - cnt;          // exclusive start
        gdesc[t * NB + bl] = st | (cnt << 16); // transposed: coalesced in k_accum
        cursor[t] = st;
    }
    __syncthreads();

#pragma unroll
    for (int i = 0; i < 4; ++i) {
        const int b   = rows[i] >> 10;
        const int pos = atomicAdd(&cursor[b], 1);
        pairs[pos] = ((unsigned long long)__float_as_uint(pv[i]) << 32) | (unsigned)rows[i];
    }
    __syncthreads();

    // fully-coalesced block-contiguous write-out
    const ulonglong2* ps = (const ulonglong2*)pairs;
    ulonglong2*       pd = (ulonglong2*)(gpairs + (size_t)bl * BPB);
#pragma unroll
    for (int i = 0; i < 2; ++i)
        pd[i * 512 + t] = ps[i * 512 + t];
}

// ---------------------------------------------------------------------------
// K3b: block b accumulates its 1024 rows in LDS from all NB segments, then
// computes sum((y-z)^2). 1024 threads: 1 segment/thread, 1 row/thread.
// ---------------------------------------------------------------------------
__global__ __launch_bounds__(1024) void k_accum(const unsigned long long* __restrict__ gpairs,
                                                const int* __restrict__ gdesc,
                                                const float* __restrict__ z,
                                                float* __restrict__ loss) {
    __shared__ float acc[RPB];
    __shared__ float red[16];
    const int t = threadIdx.x;
    const int b = blockIdx.x;
    acc[t] = 0.f;
    __syncthreads();

    if (t < NB) {
        const int d  = gdesc[b * NB + t];
        const int st = d & 0xffff;
        const int c  = d >> 16;
        const unsigned long long* p = gpairs + (size_t)t * BPB + st;
        for (int j = 0; j < c; ++j) {
            const unsigned long long pr = p[j];
            atomicAdd(&acc[(int)(pr & 1023u)], __uint_as_float((unsigned)(pr >> 32)));
        }
    }
    __syncthreads();

    const float d = acc[t] - z[b * RPB + t];
    float s = d * d;
#pragma unroll
    for (int m = 32; m >= 1; m >>= 1) s += __shfl_down(s, m);
    if ((t & 63) == 0) red[t >> 6] = s;
    __syncthreads();
    if (t == 0) {
        float tt = 0.f;
#pragma unroll
        for (int i = 0; i < 16; ++i) tt += red[i];
        atomicAdd(loss, tt);
    }
}

// --------------------------- fallback path (small ws) ----------------------
__global__ __launch_bounds__(256) void k_spmv(const int* __restrict__ idx,
                                              const float* __restrict__ vals,
                                              const float* __restrict__ w,
                                              float* __restrict__ y) {
    const int k = (blockIdx.x * 256 + threadIdx.x) * 4;
    const int4   r4 = *(const int4*)(idx + k);
    const int4   c4 = *(const int4*)(idx + NNZ_K + k);
    const float4 v4 = *(const float4*)(vals + k);
    atomicAdd(&y[r4.x], v4.x * w[c4.x]);
    atomicAdd(&y[r4.y], v4.y * w[c4.y]);
    atomicAdd(&y[r4.z], v4.z * w[c4.z]);
    atomicAdd(&y[r4.w], v4.w * w[c4.w]);
}

__global__ __launch_bounds__(256) void k_loss(const float* __restrict__ y,
                                              const float* __restrict__ z,
                                              float* __restrict__ loss) {
    const int i = blockIdx.x * 256 + threadIdx.x;
    const float4 a = ((const float4*)y)[i];
    const float4 b = ((const float4*)z)[i];
    const float dx = a.x - b.x, dy = a.y - b.y, dz = a.z - b.z, dw = a.w - b.w;
    float s = dx * dx + dy * dy + dz * dz + dw * dw;
#pragma unroll
    for (int m = 32; m >= 1; m >>= 1) s += __shfl_down(s, m);
    __shared__ float r4s[4];
    const int lane = threadIdx.x & 63, wv = threadIdx.x >> 6;
    if (lane == 0) r4s[wv] = s;
    __syncthreads();
    if (threadIdx.x == 0) atomicAdd(loss, r4s[0] + r4s[1] + r4s[2] + r4s[3]);
}

__global__ void k_fin(const float* __restrict__ loss, float* __restrict__ out) {
    out[0] = loss[0] * (1.0f / (float)NN);
}

// ---------------------------------------------------------------------------
extern "C" void kernel_launch(void* const* d_in, const int* in_sizes, int n_in,
                              void* d_out, int out_size, void* d_ws, size_t ws_size,
                              hipStream_t stream) {
    const float* leaf = (const float*)d_in[0];
    P8 u, v;
    for (int l = 0; l < 8; ++l) {
        u.p[l] = (const float*)d_in[1 + 2 * l];
        v.p[l] = (const float*)d_in[2 + 2 * l];
    }
    const int*   Aidx  = (const int*)d_in[17];
    const float* Avals = (const float*)d_in[18];
    const float* z     = (const float*)d_in[19];

    float* ws   = (float*)d_ws;
    // layout (floats): unchanged
    float* part  = ws;                     // 65536
    float* tg    = ws + 65536;             // 8192
    float* loss  = ws + 73728;             // 1 (+pad to 73792)
    float* w     = ws + 73792;             // 262144 -> end 335936
    int*   gdesc = (int*)(ws + 335936);    // NBKT*NB = 163840 -> end 499776
    unsigned long long* gpairs = (unsigned long long*)(ws + 499776); // NB*BPB*8B
    const size_t need_main = (size_t)(499776 + (size_t)NB * BPB * 2) * 4;

    k_levels_t<<<NN / 512, 512, 0, stream>>>(v, z, part);
    k_reduce_t<<<510, 64, 0, stream>>>(part, tg, loss);
    k_leaf    <<<NN / 128, 256, 0, stream>>>(leaf, z, w);   // 4 leaf-blocks/block

    if (ws_size >= need_main) {
        k_uacc <<<NN / 128, 128, 0, stream>>>(u, tg, w, nullptr);
        k_bin  <<<NB, 512, 0, stream>>>(Aidx, Avals, w, gpairs, gdesc);
        k_accum<<<NBKT, 1024, 0, stream>>>(gpairs, gdesc, z, loss);
    } else {
        float* y = ws + 335936;            // fallback: y where desc/pairs were
        k_uacc <<<NN / 128, 128, 0, stream>>>(u, tg, w, y);
        k_spmv <<<NNZ_K / 1024, 256, 0, stream>>>(Aidx, Avals, w, y);
        k_loss <<<NN / 1024, 256, 0, stream>>>(y, z, loss);
    }
    k_fin<<<1, 1, 0, stream>>>(loss, (float*)d_out);
}

// Round 3
// 355.050 us; speedup vs baseline: 1.0210x; 1.0210x over previous
//
#include <hip/hip_runtime.h>

#define NN 262144
#define RANK 16
#define NNZ_K 1310720
#define NB 512           // k_bin blocks
#define BPB 2560         // nnz per k_bin block
#define NBKT 256         // row buckets (1024 rows each)
#define RPB 1024         // rows per bucket
#define NCH 2048         // chunks in k_levels_t (128 elems each)

struct P8 { const float* p[8]; };

// ---------------------------------------------------------------------------
// K1: per-chunk partials  part[l][c][r] = sum_{j in chunk c} v_l[j][r]*z[j]
// 256-thr blocks, 2048 blocks, levels in 2 groups of 4 (VGPR <= ~85).
// ---------------------------------------------------------------------------
__global__ __launch_bounds__(256, 6) void k_levels_t(P8 v, const float* __restrict__ z,
                                                     float* __restrict__ part) {
    __shared__ float red[8][4][16];   // [level][wave][rank]
    const int tid  = threadIdx.x;
    const int base = blockIdx.x * 128;
    const int q    = tid & 3;
    const int e    = tid >> 2;        // 0..63
    const int lane = tid & 63;
    const int wv   = tid >> 6;        // 0..3

#pragma unroll
    for (int g = 0; g < 2; ++g) {
        float4 acc[4];
#pragma unroll
        for (int l = 0; l < 4; ++l) acc[l] = make_float4(0.f, 0.f, 0.f, 0.f);

#pragma unroll
        for (int it = 0; it < 2; ++it) {
            const int jl = it * 64 + e;
            const size_t j = (size_t)(base + jl);
            const float zz = z[j];
            float4 vv[4];
#pragma unroll
            for (int l = 0; l < 4; ++l)
                vv[l] = *(const float4*)(v.p[g * 4 + l] + j * RANK + q * 4);
#pragma unroll
            for (int l = 0; l < 4; ++l) {
                acc[l].x += vv[l].x * zz;
                acc[l].y += vv[l].y * zz;
                acc[l].z += vv[l].z * zz;
                acc[l].w += vv[l].w * zz;
            }
        }

#pragma unroll
        for (int l = 0; l < 4; ++l) {
            float4 a = acc[l];
#pragma unroll
            for (int m = 4; m <= 32; m <<= 1) {
                a.x += __shfl_xor(a.x, m);
                a.y += __shfl_xor(a.y, m);
                a.z += __shfl_xor(a.z, m);
                a.w += __shfl_xor(a.w, m);
            }
            if (lane < 4) *(float4*)&red[g * 4 + l][wv][lane * 4] = a;
        }
    }
    __syncthreads();

    if (tid < 128) {
        const int l = tid >> 4;
        const int r = tid & 15;
        const float s = red[l][0][r] + red[l][1][r] + red[l][2][r] + red[l][3][r];
        part[(l * NCH + blockIdx.x) * 16 + r] = s;
    }
}

// ---------------------------------------------------------------------------
// K1b: tg[(l,h)][r] = sum of partials; one block per (l,h). Zeroes loss.
// ---------------------------------------------------------------------------
__global__ __launch_bounds__(256) void k_reduce_t(const float* __restrict__ part,
                                                  float* __restrict__ tg,
                                                  float* __restrict__ loss) {
    const int b = blockIdx.x;
    if (b == 0 && threadIdx.x == 0) loss[0] = 0.f;
    const int t = b + 2;
    const int l = 30 - __clz(t);
    const int h = t - (2 << l);
    const int cnt = 1024 >> l;        // chunks per half at level l
    const int c0  = h * cnt;
    const int r = threadIdx.x & 15;
    const int g = threadIdx.x >> 4;   // 16 groups

    float s = 0.f;
    for (int c = c0 + g; c < c0 + cnt; c += 16)
        s += part[(l * NCH + c) * 16 + r];

    __shared__ float red[256];
    red[threadIdx.x] = s;
    __syncthreads();
    if (threadIdx.x < 16) {
        float ss = 0.f;
#pragma unroll
        for (int k = 0; k < 16; ++k) ss += red[k * 16 + r];
        tg[((2 << l) - 2 + h) * 16 + r] = ss;
    }
}

// ---------------------------------------------------------------------------
// K2: fused leaf + u-accumulation.
// Block = 256 thr handles 128 elements (4 leaf blocks, one per wave).
// Phase A: wave-per-leaf-block L(L^T x) via shfl butterflies -> LDS wl[128].
// Phase B: 2 threads per element (level-halves 0-3 / 4-7) -> w[i].
// ---------------------------------------------------------------------------
__global__ __launch_bounds__(256, 6) void k_w(const float* __restrict__ leaf, P8 u,
                                              const float* __restrict__ z,
                                              const float* __restrict__ tg,
                                              float* __restrict__ w,
                                              float* __restrict__ y) {
    __shared__ float wl[128];
    __shared__ float pb[128];
    __shared__ float tl[8][16];

    const int tid  = threadIdx.x;
    const int base = blockIdx.x * 128;

    // tl table (sibling t-vectors, constant across the block's 128 elems)
    if (tid < 128) {
        const int l = tid >> 4;
        const int r = tid & 15;
        const int h = base >> (17 - l);
        tl[l][r] = tg[(((2 << l) - 2) + (h ^ 1)) * 16 + r];
    }

    // ---- Phase A: leaf blocks, one wave each, no barriers inside ----
    {
        const int l6 = tid & 63;
        const int wv = tid >> 6;
        const int b  = blockIdx.x * 4 + wv;
        const int r  = l6 >> 1;

        const float* Lb = leaf + (size_t)b * 1024 + r * 32 + (l6 & 1) * 16;
        const float4 L0 = ((const float4*)Lb)[0];
        const float4 L1 = ((const float4*)Lb)[1];
        const float4 L2 = ((const float4*)Lb)[2];
        const float4 L3 = ((const float4*)Lb)[3];

        const float zl = z[b * 32 + (l6 & 31)];
        const float xr = __shfl(zl, r);

        float4 t0 = make_float4(L0.x * xr, L0.y * xr, L0.z * xr, L0.w * xr);
        float4 t1 = make_float4(L1.x * xr, L1.y * xr, L1.z * xr, L1.w * xr);
        float4 t2 = make_float4(L2.x * xr, L2.y * xr, L2.z * xr, L2.w * xr);
        float4 t3 = make_float4(L3.x * xr, L3.y * xr, L3.z * xr, L3.w * xr);

#pragma unroll
        for (int m = 2; m <= 32; m <<= 1) {
            t0.x += __shfl_xor(t0.x, m); t0.y += __shfl_xor(t0.y, m);
            t0.z += __shfl_xor(t0.z, m); t0.w += __shfl_xor(t0.w, m);
            t1.x += __shfl_xor(t1.x, m); t1.y += __shfl_xor(t1.y, m);
            t1.z += __shfl_xor(t1.z, m); t1.w += __shfl_xor(t1.w, m);
            t2.x += __shfl_xor(t2.x, m); t2.y += __shfl_xor(t2.y, m);
            t2.z += __shfl_xor(t2.z, m); t2.w += __shfl_xor(t2.w, m);
            t3.x += __shfl_xor(t3.x, m); t3.y += __shfl_xor(t3.y, m);
            t3.z += __shfl_xor(t3.z, m); t3.w += __shfl_xor(t3.w, m);
        }

        float yp = L0.x * t0.x + L0.y * t0.y + L0.z * t0.z + L0.w * t0.w
                 + L1.x * t1.x + L1.y * t1.y + L1.z * t1.z + L1.w * t1.w
                 + L2.x * t2.x + L2.y * t2.y + L2.z * t2.z + L2.w * t2.w
                 + L3.x * t3.x + L3.y * t3.y + L3.z * t3.z + L3.w * t3.w;
        yp += __shfl_xor(yp, 1);

        const float w0  = yp + 1e-4f * xr;
        const float out = __shfl(w0, (l6 & 31) * 2);
        if (l6 < 32) wl[wv * 32 + l6] = out;
    }
    __syncthreads();

    // ---- Phase B: 2 threads per element, 4 levels each ----
    const int half = tid >> 7;            // 0: levels 0-3, 1: levels 4-7
    const int e    = tid & 127;
    const size_t i = (size_t)(base + e);
    const int l0   = half * 4;

    float accs[4];
#pragma unroll
    for (int lp = 0; lp < 2; ++lp) {
        const int l = l0 + lp * 2;
        float4 a[8];
        {
            const float4* up0 = (const float4*)(u.p[l] + i * RANK);
            const float4* up1 = (const float4*)(u.p[l + 1] + i * RANK);
#pragma unroll
            for (int k = 0; k < 4; ++k) a[k]     = up0[k];
#pragma unroll
            for (int k = 0; k < 4; ++k) a[4 + k] = up1[k];
        }
#pragma unroll
        for (int s = 0; s < 2; ++s) {
            const float4 t0 = *(const float4*)&tl[l + s][0];
            const float4 t1 = *(const float4*)&tl[l + s][4];
            const float4 t2 = *(const float4*)&tl[l + s][8];
            const float4 t3 = *(const float4*)&tl[l + s][12];
            const float4* av = &a[s * 4];
            accs[lp * 2 + s] = av[0].x * t0.x + av[0].y * t0.y + av[0].z * t0.z + av[0].w * t0.w
                             + av[1].x * t1.x + av[1].y * t1.y + av[1].z * t1.z + av[1].w * t1.w
                             + av[2].x * t2.x + av[2].y * t2.y + av[2].z * t2.z + av[2].w * t2.w
                             + av[3].x * t3.x + av[3].y * t3.y + av[3].z * t3.z + av[3].w * t3.w;
        }
    }
    const float sum = (accs[0] + accs[1]) + (accs[2] + accs[3]);
    if (half) pb[e] = sum;
    __syncthreads();
    if (!half) {
        w[i] = wl[e] + sum + pb[e];
        if (y) y[i] = 0.f;
    }
}

// ---------------------------------------------------------------------------
// K3a: bucket-sort (row, val*w[col]) pairs. 512 blocks x 640 threads.
// ---------------------------------------------------------------------------
__global__ __launch_bounds__(640) void k_bin(const int* __restrict__ idx,
                                             const float* __restrict__ vals,
                                             const float* __restrict__ w,
                                             unsigned long long* __restrict__ gpairs,
                                             int* __restrict__ gdesc) {
    __shared__ unsigned long long pairs[BPB];   // 20 KB
    __shared__ int hist[NBKT];
    __shared__ int scan[NBKT];
    __shared__ int cursor[NBKT];

    const int t  = threadIdx.x;
    const int bl = blockIdx.x;
    const int base = bl * BPB;

    if (t < NBKT) hist[t] = 0;
    __syncthreads();

    int   rows[4];
    float pv[4];
    {
        const int k = base + t * 4;
        const int4   r4 = *(const int4*)(idx + k);
        const int4   c4 = *(const int4*)(idx + NNZ_K + k);
        const float4 v4 = *(const float4*)(vals + k);
        rows[0] = r4.x; pv[0] = v4.x * w[c4.x];
        rows[1] = r4.y; pv[1] = v4.y * w[c4.y];
        rows[2] = r4.z; pv[2] = v4.z * w[c4.z];
        rows[3] = r4.w; pv[3] = v4.w * w[c4.w];
        atomicAdd(&hist[r4.x >> 10], 1);
        atomicAdd(&hist[r4.y >> 10], 1);
        atomicAdd(&hist[r4.z >> 10], 1);
        atomicAdd(&hist[r4.w >> 10], 1);
    }
    __syncthreads();

    // inclusive Hillis-Steele scan over 256 buckets (first 256 threads)
    int cnt = 0;
    if (t < NBKT) { cnt = hist[t]; scan[t] = cnt; }
    __syncthreads();
    for (int off = 1; off < NBKT; off <<= 1) {
        int add = 0;
        if (t >= off && t < NBKT) add = scan[t - off];
        __syncthreads();
        if (t < NBKT) scan[t] += add;
        __syncthreads();
    }
    if (t < NBKT) {
        const int st = scan[t] - cnt;          // exclusive start
        gdesc[t * NB + bl] = st | (cnt << 16); // transposed: coalesced in k_accum
        cursor[t] = st;
    }
    __syncthreads();

#pragma unroll
    for (int i = 0; i < 4; ++i) {
        const int b   = rows[i] >> 10;
        const int pos = atomicAdd(&cursor[b], 1);
        pairs[pos] = ((unsigned long long)__float_as_uint(pv[i]) << 32) | (unsigned)rows[i];
    }
    __syncthreads();

    // fully-coalesced block-contiguous write-out (1280 ulonglong2)
    const ulonglong2* ps = (const ulonglong2*)pairs;
    ulonglong2*       pd = (ulonglong2*)(gpairs + (size_t)bl * BPB);
#pragma unroll
    for (int i = 0; i < 2; ++i)
        pd[i * 640 + t] = ps[i * 640 + t];
}

// ---------------------------------------------------------------------------
// K3b: block b accumulates its 1024 rows in LDS from all NB segments;
// 1024 threads = 2 threads per segment; then sum((y-z)^2) 1 row/thread.
// ---------------------------------------------------------------------------
__global__ __launch_bounds__(1024) void k_accum(const unsigned long long* __restrict__ gpairs,
                                                const int* __restrict__ gdesc,
                                                const float* __restrict__ z,
                                                float* __restrict__ loss) {
    __shared__ float acc[RPB];
    __shared__ float red[16];
    const int t = threadIdx.x;
    const int b = blockIdx.x;
    acc[t] = 0.f;
    __syncthreads();

    {
        const int s  = t >> 1;        // segment (k_bin block), 0..511
        const int h  = t & 1;
        const int d  = gdesc[b * NB + s];
        const int st = d & 0xffff;
        const int c  = d >> 16;
        const unsigned long long* p = gpairs + (size_t)s * BPB + st;
        for (int j = h; j < c; j += 2) {
            const unsigned long long pr = p[j];
            atomicAdd(&acc[(int)(pr & 1023u)], __uint_as_float((unsigned)(pr >> 32)));
        }
    }
    __syncthreads();

    const float d = acc[t] - z[b * RPB + t];
    float s = d * d;
#pragma unroll
    for (int m = 32; m >= 1; m >>= 1) s += __shfl_down(s, m);
    if ((t & 63) == 0) red[t >> 6] = s;
    __syncthreads();
    if (t == 0) {
        float tt = 0.f;
#pragma unroll
        for (int i = 0; i < 16; ++i) tt += red[i];
        atomicAdd(loss, tt);
    }
}

// --------------------------- fallback path (small ws) ----------------------
__global__ __launch_bounds__(256) void k_spmv(const int* __restrict__ idx,
                                              const float* __restrict__ vals,
                                              const float* __restrict__ w,
                                              float* __restrict__ y) {
    const int k = (blockIdx.x * 256 + threadIdx.x) * 4;
    const int4   r4 = *(const int4*)(idx + k);
    const int4   c4 = *(const int4*)(idx + NNZ_K + k);
    const float4 v4 = *(const float4*)(vals + k);
    atomicAdd(&y[r4.x], v4.x * w[c4.x]);
    atomicAdd(&y[r4.y], v4.y * w[c4.y]);
    atomicAdd(&y[r4.z], v4.z * w[c4.z]);
    atomicAdd(&y[r4.w], v4.w * w[c4.w]);
}

__global__ __launch_bounds__(256) void k_loss(const float* __restrict__ y,
                                              const float* __restrict__ z,
                                              float* __restrict__ loss) {
    const int i = blockIdx.x * 256 + threadIdx.x;
    const float4 a = ((const float4*)y)[i];
    const float4 b = ((const float4*)z)[i];
    const float dx = a.x - b.x, dy = a.y - b.y, dz = a.z - b.z, dw = a.w - b.w;
    float s = dx * dx + dy * dy + dz * dz + dw * dw;
#pragma unroll
    for (int m = 32; m >= 1; m >>= 1) s += __shfl_down(s, m);
    __shared__ float r4s[4];
    const int lane = threadIdx.x & 63, wv = threadIdx.x >> 6;
    if (lane == 0) r4s[wv] = s;
    __syncthreads();
    if (threadIdx.x == 0) atomicAdd(loss, r4s[0] + r4s[1] + r4s[2] + r4s[3]);
}

__global__ void k_fin(const float* __restrict__ loss, float* __restrict__ out) {
    out[0] = loss[0] * (1.0f / (float)NN);
}

// ---------------------------------------------------------------------------
extern "C" void kernel_launch(void* const* d_in, const int* in_sizes, int n_in,
                              void* d_out, int out_size, void* d_ws, size_t ws_size,
                              hipStream_t stream) {
    const float* leaf = (const float*)d_in[0];
    P8 u, v;
    for (int l = 0; l < 8; ++l) {
        u.p[l] = (const float*)d_in[1 + 2 * l];
        v.p[l] = (const float*)d_in[2 + 2 * l];
    }
    const int*   Aidx  = (const int*)d_in[17];
    const float* Avals = (const float*)d_in[18];
    const float* z     = (const float*)d_in[19];

    float* ws   = (float*)d_ws;
    // layout (floats):
    float* part  = ws;                     // 8*NCH*16 = 262144
    float* tg    = ws + 262144;            // 8192
    float* loss  = ws + 270336;            // 1 (pad to 270400)
    float* w     = ws + 270400;            // 262144 -> 532544
    int*   gdesc = (int*)(ws + 532544);    // NBKT*NB = 131072 -> 663616
    unsigned long long* gpairs = (unsigned long long*)(ws + 663616); // NB*BPB*8B
    const size_t need_main = (size_t)(663616 + (size_t)NB * BPB * 2) * 4;

    k_levels_t<<<NCH, 256, 0, stream>>>(v, z, part);
    k_reduce_t<<<510, 256, 0, stream>>>(part, tg, loss);

    if (ws_size >= need_main) {
        k_w    <<<NN / 128, 256, 0, stream>>>(leaf, u, z, tg, w, nullptr);
        k_bin  <<<NB, 640, 0, stream>>>(Aidx, Avals, w, gpairs, gdesc);
        k_accum<<<NBKT, 1024, 0, stream>>>(gpairs, gdesc, z, loss);
    } else {
        float* y = ws + 532544;            // fallback: y where gdesc was
        k_w    <<<NN / 128, 256, 0, stream>>>(leaf, u, z, tg, w, y);
        k_spmv <<<NNZ_K / 1024, 256, 0, stream>>>(Aidx, Avals, w, y);
        k_loss <<<NN / 1024, 256, 0, stream>>>(y, z, loss);
    }
    k_fin<<<1, 1, 0, stream>>>(loss, (float*)d_out);
}